// Round 1
// baseline (356.359 us; speedup 1.0000x reference)
//
#include <hip/hip_runtime.h>
#include <math.h>

// ---------------------------------------------------------------------------
// MultiModalEncoder collapses algebraically:
//   softmax of constant score matrices -> exactly 0.5 each
//   res_mv == res_pc == 0.5*(v_mv+v_pc) + max(v_mv,v_pc)          (q/k dead)
//   stage-2 attention of identical rows -> 2*v_c
//   h = r2 @ (Wv_c@Wp) + (2*bv_c@Wp + bp),  r2 = v_mv+v_pc+2*max(v_mv,v_pc)
// Then LayerNorm -> SELU -> L2 normalize per row.
//
// Numerics: f32 values split into bf16 hi+lo; each matmul done as
// 3 bf16 MFMA products (hi*hi + lo*hi + hi*lo) with f32 accumulation
// -> ~2^-16 relative error, matches the f32 reference to ~1e-5.
// ---------------------------------------------------------------------------

typedef float f32x4 __attribute__((ext_vector_type(4)));
typedef short s16x8 __attribute__((ext_vector_type(8)));   // 8 bf16 (4 VGPRs)

__device__ __forceinline__ unsigned short f2bf(float x) {
    unsigned u = __builtin_bit_cast(unsigned, x);
    unsigned r = u + 0x7fffu + ((u >> 16) & 1u);           // RNE
    return (unsigned short)(r >> 16);
}
__device__ __forceinline__ float bf2f(unsigned short h) {
    return __builtin_bit_cast(float, ((unsigned)h) << 16);
}

// ---------------- prep kernel 1: W2 = Wv_c @ Wp ; b2 = 2*(bv_c@Wp) + bp ----
__global__ void prep_w2(const float* __restrict__ Wv_c, const float* __restrict__ Wp,
                        const float* __restrict__ bv_c, const float* __restrict__ bp,
                        float* __restrict__ W2, float* __restrict__ b2) {
    int j = threadIdx.x;            // 0..127 (output col)
    int i = blockIdx.x;             // 0..128 (row; 128 == bias row)
    if (i < 128) {
        float s = 0.f;
        for (int k = 0; k < 128; ++k) s = fmaf(Wv_c[i * 128 + k], Wp[k * 128 + j], s);
        W2[i * 128 + j] = s;
    } else {
        float s = 0.f;
        for (int k = 0; k < 128; ++k) s = fmaf(bv_c[k], Wp[k * 128 + j], s);
        b2[j] = 2.f * s + bp[j];
    }
}

// ---------------- prep kernel 2: pack W[K][128] into MFMA B-frag order -----
// frag f = c*8 + t  (c = K-chunk of 32, t = N-tile of 16)
// layout: out[f*1024 + 0*512 + l*8 + i] = hi,  +512 = lo
// where lane l needs B[k = c*32 + (l>>4)*8 + i][col = t*16 + (l&15)]
__global__ void pack_frags(const float* __restrict__ W, unsigned short* __restrict__ out) {
    int f = blockIdx.x;
    int l = threadIdx.x;            // 0..63
    int c = f >> 3, t = f & 7;
    int col = t * 16 + (l & 15);
    int k0 = c * 32 + (l >> 4) * 8;
    unsigned short hi[8], lo[8];
    #pragma unroll
    for (int i = 0; i < 8; ++i) {
        float x = W[(k0 + i) * 128 + col];
        unsigned short h = f2bf(x);
        hi[i] = h;
        lo[i] = f2bf(x - bf2f(h));
    }
    unsigned short* base = out + (size_t)f * 1024 + (size_t)l * 8;
    #pragma unroll
    for (int i = 0; i < 8; ++i) base[i] = hi[i];
    #pragma unroll
    for (int i = 0; i < 8; ++i) base[512 + i] = lo[i];
}

// ---------------- main fused kernel ----------------------------------------
// 256 threads = 4 waves; each wave computes 32 rows (2 x 16-row M-subtiles).
// Grid = 131072/128 = 1024 blocks.
__launch_bounds__(256, 2)
__global__ void fused_main(const float* __restrict__ mv, const float* __restrict__ pc,
                           const unsigned short* __restrict__ Fmv,
                           const unsigned short* __restrict__ Fpc,
                           const unsigned short* __restrict__ Fw2,
                           const float* __restrict__ b_mv, const float* __restrict__ b_pc,
                           const float* __restrict__ b2v,
                           const float* __restrict__ ln_g, const float* __restrict__ ln_b,
                           float* __restrict__ out) {
    __shared__ unsigned int r2lds[4][32][128];   // 64 KB: per-wave (lo<<16|hi) r2
    const int tid = threadIdx.x;
    const int wv  = tid >> 6;
    const int l   = tid & 63;
    const int lg  = l >> 4;        // lane group 0..3
    const int ll  = l & 15;        // lane low
    const int rowbase = blockIdx.x * 128 + wv * 32;

    const f32x4 vz = {0.f, 0.f, 0.f, 0.f};
    f32x4 acc1[2][8], acc2[2][8];
    #pragma unroll
    for (int s = 0; s < 2; ++s)
        #pragma unroll
        for (int t = 0; t < 8; ++t) { acc1[s][t] = vz; acc2[s][t] = vz; }

    // ---------------- stage 1a: X1 = mv @ Wv_mv (K=256) --------------------
    #pragma unroll 1
    for (int c = 0; c < 8; ++c) {
        s16x8 ah[2], al[2];
        #pragma unroll
        for (int s = 0; s < 2; ++s) {
            const float* ap = mv + (size_t)(rowbase + s * 16 + ll) * 256 + c * 32 + lg * 8;
            f32x4 x0 = *(const f32x4*)ap;
            f32x4 x1 = *(const f32x4*)(ap + 4);
            #pragma unroll
            for (int i = 0; i < 4; ++i) {
                unsigned short h0 = f2bf(x0[i]);
                ah[s][i] = (short)h0;
                al[s][i] = (short)f2bf(x0[i] - bf2f(h0));
                unsigned short h1 = f2bf(x1[i]);
                ah[s][4 + i] = (short)h1;
                al[s][4 + i] = (short)f2bf(x1[i] - bf2f(h1));
            }
        }
        const unsigned short* fb = Fmv + (size_t)c * 8192 + (size_t)l * 8;
        #pragma unroll
        for (int t = 0; t < 8; ++t) {
            s16x8 bh = *(const s16x8*)(fb + t * 1024);
            s16x8 bl = *(const s16x8*)(fb + t * 1024 + 512);
            #pragma unroll
            for (int s = 0; s < 2; ++s) {
                acc1[s][t] = __builtin_amdgcn_mfma_f32_16x16x32_bf16(ah[s], bh, acc1[s][t], 0, 0, 0);
                acc1[s][t] = __builtin_amdgcn_mfma_f32_16x16x32_bf16(al[s], bh, acc1[s][t], 0, 0, 0);
                acc1[s][t] = __builtin_amdgcn_mfma_f32_16x16x32_bf16(ah[s], bl, acc1[s][t], 0, 0, 0);
            }
        }
    }

    // ---------------- stage 1b: X2 = pc @ Wv_pc (K=128) --------------------
    #pragma unroll 1
    for (int c = 0; c < 4; ++c) {
        s16x8 ah[2], al[2];
        #pragma unroll
        for (int s = 0; s < 2; ++s) {
            const float* ap = pc + (size_t)(rowbase + s * 16 + ll) * 128 + c * 32 + lg * 8;
            f32x4 x0 = *(const f32x4*)ap;
            f32x4 x1 = *(const f32x4*)(ap + 4);
            #pragma unroll
            for (int i = 0; i < 4; ++i) {
                unsigned short h0 = f2bf(x0[i]);
                ah[s][i] = (short)h0;
                al[s][i] = (short)f2bf(x0[i] - bf2f(h0));
                unsigned short h1 = f2bf(x1[i]);
                ah[s][4 + i] = (short)h1;
                al[s][4 + i] = (short)f2bf(x1[i] - bf2f(h1));
            }
        }
        const unsigned short* fb = Fpc + (size_t)c * 8192 + (size_t)l * 8;
        #pragma unroll
        for (int t = 0; t < 8; ++t) {
            s16x8 bh = *(const s16x8*)(fb + t * 1024);
            s16x8 bl = *(const s16x8*)(fb + t * 1024 + 512);
            #pragma unroll
            for (int s = 0; s < 2; ++s) {
                acc2[s][t] = __builtin_amdgcn_mfma_f32_16x16x32_bf16(ah[s], bh, acc2[s][t], 0, 0, 0);
                acc2[s][t] = __builtin_amdgcn_mfma_f32_16x16x32_bf16(al[s], bh, acc2[s][t], 0, 0, 0);
                acc2[s][t] = __builtin_amdgcn_mfma_f32_16x16x32_bf16(ah[s], bl, acc2[s][t], 0, 0, 0);
            }
        }
    }

    // ---------- combine: r2 = x1 + x2 + 2*max(x1,x2); stash hi/lo in LDS ---
    // C-frag layout: row = (l>>4)*4 + j (+ s*16), col = l&15 (+ t*16)
    #pragma unroll
    for (int t = 0; t < 8; ++t) {
        float bm  = b_mv[t * 16 + ll];
        float bpc = b_pc[t * 16 + ll];
        #pragma unroll
        for (int s = 0; s < 2; ++s) {
            #pragma unroll
            for (int j = 0; j < 4; ++j) {
                float x1 = acc1[s][t][j] + bm;
                float x2 = acc2[s][t][j] + bpc;
                float r2 = (x1 + x2) + 2.f * fmaxf(x1, x2);
                unsigned short h  = f2bf(r2);
                unsigned short lo = f2bf(r2 - bf2f(h));
                r2lds[wv][s * 16 + lg * 4 + j][t * 16 + ll] = ((unsigned)lo << 16) | (unsigned)h;
            }
        }
    }
    __syncthreads();   // per-wave region, but keep a hard fence before re-read

    // ---------------- stage 2: H = r2 @ W2 (K=128) -------------------------
    f32x4 acch[2][8];
    #pragma unroll
    for (int s = 0; s < 2; ++s)
        #pragma unroll
        for (int t = 0; t < 8; ++t) acch[s][t] = vz;

    #pragma unroll 1
    for (int c = 0; c < 4; ++c) {
        s16x8 ah[2], al[2];
        #pragma unroll
        for (int s = 0; s < 2; ++s) {
            const unsigned int* rp = &r2lds[wv][s * 16 + ll][c * 32 + lg * 8];
            #pragma unroll
            for (int i = 0; i < 8; ++i) {
                unsigned u = rp[i];
                ah[s][i] = (short)(u & 0xffffu);
                al[s][i] = (short)(u >> 16);
            }
        }
        const unsigned short* fb = Fw2 + (size_t)c * 8192 + (size_t)l * 8;
        #pragma unroll
        for (int t = 0; t < 8; ++t) {
            s16x8 bh = *(const s16x8*)(fb + t * 1024);
            s16x8 bl = *(const s16x8*)(fb + t * 1024 + 512);
            #pragma unroll
            for (int s = 0; s < 2; ++s) {
                acch[s][t] = __builtin_amdgcn_mfma_f32_16x16x32_bf16(ah[s], bh, acch[s][t], 0, 0, 0);
                acch[s][t] = __builtin_amdgcn_mfma_f32_16x16x32_bf16(al[s], bh, acch[s][t], 0, 0, 0);
                acch[s][t] = __builtin_amdgcn_mfma_f32_16x16x32_bf16(ah[s], bl, acch[s][t], 0, 0, 0);
            }
        }
    }

    // ---------------- epilogue: +b2, LayerNorm, SELU, L2-normalize ---------
    float b2c[8], bg[8], bb[8];
    #pragma unroll
    for (int t = 0; t < 8; ++t) {
        b2c[t] = b2v[t * 16 + ll];
        bg[t]  = ln_g[t * 16 + ll];
        bb[t]  = ln_b[t * 16 + ll];
    }
    #pragma unroll
    for (int s = 0; s < 2; ++s) {
        #pragma unroll
        for (int j = 0; j < 4; ++j) {
            float v[8];
            float sum = 0.f, ssq = 0.f;
            #pragma unroll
            for (int t = 0; t < 8; ++t) {
                float h = acch[s][t][j] + b2c[t];
                v[t] = h;
                sum += h;
                ssq = fmaf(h, h, ssq);
            }
            #pragma unroll
            for (int o = 1; o < 16; o <<= 1) {
                sum += __shfl_xor(sum, o);
                ssq += __shfl_xor(ssq, o);
            }
            float mu  = sum * 0.0078125f;                   // /128
            float var = ssq * 0.0078125f - mu * mu;
            float rs  = 1.f / sqrtf(var + 1e-5f);
            float s2  = 0.f;
            #pragma unroll
            for (int t = 0; t < 8; ++t) {
                float hn = (v[t] - mu) * rs * bg[t] + bb[t];
                float m  = hn > 0.f ? hn : 1.6732632423543772f * expm1f(hn);
                m = 1.0507009873554805f * m;                // selu scale
                v[t] = m;
                s2 = fmaf(m, m, s2);
            }
            #pragma unroll
            for (int o = 1; o < 16; o <<= 1) s2 += __shfl_xor(s2, o);
            float sc = 1.f / (sqrtf(s2) + 1e-9f);
            int row = rowbase + s * 16 + lg * 4 + j;
            float* op = out + (size_t)row * 128 + ll;
            #pragma unroll
            for (int t = 0; t < 8; ++t) op[t * 16] = v[t] * sc;
        }
    }
}

// ---------------------------------------------------------------------------
extern "C" void kernel_launch(void* const* d_in, const int* in_sizes, int n_in,
                              void* d_out, int out_size, void* d_ws, size_t ws_size,
                              hipStream_t stream) {
    const float* mv    = (const float*)d_in[0];
    const float* pc    = (const float*)d_in[1];
    const float* Wv_mv = (const float*)d_in[6];
    const float* bv_mv = (const float*)d_in[7];
    const float* Wv_pc = (const float*)d_in[12];
    const float* bv_pc = (const float*)d_in[13];
    const float* Wv_c  = (const float*)d_in[18];
    const float* bv_c  = (const float*)d_in[19];
    const float* Wp    = (const float*)d_in[20];
    const float* bp    = (const float*)d_in[21];
    const float* ln_g  = (const float*)d_in[22];
    const float* ln_b  = (const float*)d_in[23];
    float* out = (float*)d_out;

    char* ws = (char*)d_ws;
    float* W2 = (float*)ws;                                   // 128*128 f32 = 64 KB
    float* b2 = (float*)(ws + 65536);                         // 128 f32
    unsigned short* Fmv = (unsigned short*)(ws + 66048);      // 64 frag-pairs = 128 KB
    unsigned short* Fpc = Fmv + 65536;                        // 32 frag-pairs = 64 KB
    unsigned short* Fw2 = Fpc + 32768;                        // 32 frag-pairs = 64 KB

    prep_w2<<<129, 128, 0, stream>>>(Wv_c, Wp, bv_c, bp, W2, b2);
    pack_frags<<<64, 64, 0, stream>>>(Wv_mv, Fmv);
    pack_frags<<<32, 64, 0, stream>>>(Wv_pc, Fpc);
    pack_frags<<<32, 64, 0, stream>>>(W2, Fw2);               // after prep_w2 (stream order)

    fused_main<<<1024, 256, 0, stream>>>(mv, pc, Fmv, Fpc, Fw2,
                                         bv_mv, bv_pc, b2, ln_g, ln_b, out);
}